// Round 1
// baseline (229.263 us; speedup 1.0000x reference)
//
#include <hip/hip_runtime.h>
#include <hip/hip_bf16.h>

#define D_MODEL 1024
#define NHEAD   16
#define HDK     64
#define SEQ     2048
#define BATCH   2
#define BS      (BATCH * SEQ)

typedef __attribute__((ext_vector_type(8))) short bf16x8;
typedef __attribute__((ext_vector_type(4))) float f32x4;

__device__ __forceinline__ unsigned short f2bf(float f) {
    unsigned u = __builtin_bit_cast(unsigned, f);
    u += 0x7fffu + ((u >> 16) & 1u);          // round-to-nearest-even
    return (unsigned short)(u >> 16);
}

// pack hi16(x):hi16(y) -> (hi16(y)<<16)|hi16(x) with one v_perm_b32 (truncation)
__device__ __forceinline__ unsigned pack_hi(float x, float y) {
    return __builtin_amdgcn_perm(__builtin_bit_cast(unsigned, y),
                                 __builtin_bit_cast(unsigned, x), 0x07060302u);
}

typedef const void __attribute__((address_space(1))) gas_void;
typedef void __attribute__((address_space(3))) las_void;

__device__ __forceinline__ void gll16(const void* g, void* l) {
    __builtin_amdgcn_global_load_lds((gas_void*)g, (las_void*)l, 16, 0, 0);
}

// Barrier that does NOT drain vmcnt: staging here is reg->LDS, so cross-wave
// visibility only needs lgkmcnt(0). Keeps K/V global prefetches in flight
// across the barrier (the compiler's own dependency-vmcnt covers their use).
__device__ __forceinline__ void tile_barrier() {
    asm volatile("s_waitcnt lgkmcnt(0)" ::: "memory");
    __builtin_amdgcn_s_barrier();
}

// ---------------------------------------------------------------------------
// fp32 -> bf16 casts
// ---------------------------------------------------------------------------
__device__ __forceinline__ void cast_body(const float* __restrict__ src,
                                          unsigned short* __restrict__ dst, int i) {
    const float4* p = (const float4*)src + (size_t)i * 2;
    float4 a = p[0], b = p[1];
    ushort4 lo = make_ushort4(f2bf(a.x), f2bf(a.y), f2bf(a.z), f2bf(a.w));
    ushort4 hi = make_ushort4(f2bf(b.x), f2bf(b.y), f2bf(b.z), f2bf(b.w));
    ushort4* q = (ushort4*)dst + (size_t)i * 2;
    q[0] = lo; q[1] = hi;
}

__global__ __launch_bounds__(256)
void cast_act(const float* a, const float* b, const float* c,
              unsigned short* oa, unsigned short* ob, unsigned short* oc, int n8) {
    int i = blockIdx.x * 256 + threadIdx.x;
    if (i >= n8) return;
    const float* s = blockIdx.y == 0 ? a : blockIdx.y == 1 ? b : c;
    unsigned short* d = blockIdx.y == 0 ? oa : blockIdx.y == 1 ? ob : oc;
    cast_body(s, d, i);
}

__global__ __launch_bounds__(256)
void cast_wt(const float* a, const float* b, const float* c, const float* dd,
             unsigned short* oa, unsigned short* ob, unsigned short* oc, unsigned short* od, int n8) {
    int i = blockIdx.x * 256 + threadIdx.x;
    if (i >= n8) return;
    const float* s = blockIdx.y == 0 ? a : blockIdx.y == 1 ? b : blockIdx.y == 2 ? c : dd;
    unsigned short* d = blockIdx.y == 0 ? oa : blockIdx.y == 1 ? ob : blockIdx.y == 2 ? oc : od;
    cast_body(s, d, i);
}

// ---------------------------------------------------------------------------
// GEMM K-loop, BM=128 BN=128 BK=64, 256 thr, wave -> 64x64 quadrant.
// ---------------------------------------------------------------------------
__device__ __forceinline__ void gemm_kloop128(const unsigned short* __restrict__ X,
                                              const unsigned short* __restrict__ W,
                                              unsigned short* As, unsigned short* Bs,
                                              int bm, int bn, f32x4 acc[4][4]) {
    const int t    = threadIdx.x;
    const int w    = t >> 6;
    const int L    = t & 63;
    const int quad = L >> 4;
    const int lm   = L & 15;
    const int r8   = L >> 3;
    const int sl   = L & 7;
    const int xcol = ((sl ^ r8) & 7) * 8;
    const int wr   = (w >> 1) * 64;
    const int wc   = (w & 1) * 64;

    for (int kt = 0; kt < D_MODEL; kt += 64) {
        __syncthreads();
        #pragma unroll
        for (int i = 0; i < 4; ++i) {
            int c = w * 4 + i;
            gll16(X + (size_t)(bm + c * 8 + r8) * D_MODEL + kt + xcol, &As[c * 512]);
        }
        #pragma unroll
        for (int i = 0; i < 4; ++i) {
            int c = w * 4 + i;
            gll16(W + (size_t)(bn + c * 8 + r8) * D_MODEL + kt + xcol, &Bs[c * 512]);
        }
        __syncthreads();

        #pragma unroll
        for (int ch = 0; ch < 2; ++ch) {
            bf16x8 af[4], bfr[4];
            #pragma unroll
            for (int ms = 0; ms < 4; ++ms) {
                int row = wr + ms * 16 + lm;
                af[ms] = *(const bf16x8*)&As[row * 64 + (((ch * 4 + quad) ^ (row & 7)) * 8)];
            }
            #pragma unroll
            for (int ns = 0; ns < 4; ++ns) {
                int row = wc + ns * 16 + lm;
                bfr[ns] = *(const bf16x8*)&Bs[row * 64 + (((ch * 4 + quad) ^ (row & 7)) * 8)];
            }
            #pragma unroll
            for (int ms = 0; ms < 4; ++ms)
                #pragma unroll
                for (int ns = 0; ns < 4; ++ns)
                    acc[ms][ns] = __builtin_amdgcn_mfma_f32_16x16x32_bf16(
                        af[ms], bfr[ns], acc[ms][ns], 0, 0, 0);
        }
    }
}

// BM=128 BN=64 variant (more blocks for the small out_gemm)
__device__ __forceinline__ void gemm_kloop64(const unsigned short* __restrict__ X,
                                             const unsigned short* __restrict__ W,
                                             unsigned short* As, unsigned short* Bs,
                                             int bm, int bn, f32x4 acc[2][4]) {
    const int t    = threadIdx.x;
    const int w    = t >> 6;
    const int L    = t & 63;
    const int quad = L >> 4;
    const int lm   = L & 15;
    const int r8   = L >> 3;
    const int sl   = L & 7;
    const int xcol = ((sl ^ r8) & 7) * 8;

    for (int kt = 0; kt < D_MODEL; kt += 64) {
        __syncthreads();
        #pragma unroll
        for (int i = 0; i < 4; ++i) {
            int c = w * 4 + i;
            gll16(X + (size_t)(bm + c * 8 + r8) * D_MODEL + kt + xcol, &As[c * 512]);
        }
        #pragma unroll
        for (int i = 0; i < 2; ++i) {
            int c = w * 2 + i;
            gll16(W + (size_t)(bn + c * 8 + r8) * D_MODEL + kt + xcol, &Bs[c * 512]);
        }
        __syncthreads();

        #pragma unroll
        for (int ch = 0; ch < 2; ++ch) {
            bf16x8 af[2], bfr[4];
            #pragma unroll
            for (int ms = 0; ms < 2; ++ms) {
                int row = w * 32 + ms * 16 + lm;
                af[ms] = *(const bf16x8*)&As[row * 64 + (((ch * 4 + quad) ^ (row & 7)) * 8)];
            }
            #pragma unroll
            for (int ns = 0; ns < 4; ++ns) {
                int row = ns * 16 + lm;
                bfr[ns] = *(const bf16x8*)&Bs[row * 64 + (((ch * 4 + quad) ^ (row & 7)) * 8)];
            }
            #pragma unroll
            for (int ms = 0; ms < 2; ++ms)
                #pragma unroll
                for (int ns = 0; ns < 4; ++ns)
                    acc[ms][ns] = __builtin_amdgcn_mfma_f32_16x16x32_bf16(
                        af[ms], bfr[ns], acc[ms][ns], 0, 0, 0);
        }
    }
}

// ---------------------------------------------------------------------------
// Fused Q/K/V projections. z=0: Q (x 0.125*log2(e) -> exp2-domain softmax,
// row-major), z=1: K (row-major), z=2: V transposed per head.
// ---------------------------------------------------------------------------
__global__ __launch_bounds__(256, 3)
void proj_gemm(const unsigned short* __restrict__ qx, const unsigned short* __restrict__ kx,
               const unsigned short* __restrict__ vx, const unsigned short* __restrict__ wq,
               const unsigned short* __restrict__ wk, const unsigned short* __restrict__ wv,
               unsigned short* __restrict__ Qp, unsigned short* __restrict__ Kp,
               unsigned short* __restrict__ VT) {
    __shared__ __align__(16) unsigned short As[128 * 64];
    __shared__ __align__(16) unsigned short Bs[128 * 64];

    const int p = blockIdx.z;
    const unsigned short* X = p == 0 ? qx : p == 1 ? kx : vx;
    const unsigned short* W = p == 0 ? wq : p == 1 ? wk : wv;
    const int bm = blockIdx.y * 128, bn = blockIdx.x * 128;

    f32x4 acc[4][4];
    #pragma unroll
    for (int ms = 0; ms < 4; ++ms)
        #pragma unroll
        for (int ns = 0; ns < 4; ++ns)
            acc[ms][ns] = (f32x4){0.f, 0.f, 0.f, 0.f};

    gemm_kloop128(X, W, As, Bs, bm, bn, acc);

    const int t = threadIdx.x, w = t >> 6, L = t & 63, quad = L >> 4, lm = L & 15;
    const int wr = (w >> 1) * 64, wc = (w & 1) * 64;
    if (p == 2) {
        const int b    = bm >> 11;
        const int s_in = (bm & (SEQ - 1)) + wr;
        #pragma unroll
        for (int ms = 0; ms < 4; ++ms)
            #pragma unroll
            for (int ns = 0; ns < 4; ++ns) {
                int dg = bn + wc + ns * 16 + lm;
                int h  = dg >> 6, d = dg & 63;
                ushort4 pk = make_ushort4(f2bf(acc[ms][ns][0]), f2bf(acc[ms][ns][1]),
                                          f2bf(acc[ms][ns][2]), f2bf(acc[ms][ns][3]));
                *(ushort4*)&VT[((size_t)((b * NHEAD + h) * HDK + d)) * SEQ +
                               s_in + ms * 16 + quad * 4] = pk;
            }
    } else {
        unsigned short* Y = p == 0 ? Qp : Kp;
        // 0.125 * log2(e): softmax runs in exp2 domain (saves a v_mul per exp)
        const float scl = p == 0 ? 0.18033688011112042f : 1.0f;
        #pragma unroll
        for (int ms = 0; ms < 4; ++ms)
            #pragma unroll
            for (int ns = 0; ns < 4; ++ns)
                #pragma unroll
                for (int r = 0; r < 4; ++r)
                    Y[(size_t)(bm + wr + ms * 16 + quad * 4 + r) * D_MODEL +
                      bn + wc + ns * 16 + lm] = f2bf(acc[ms][ns][r] * scl);
    }
}

__global__ __launch_bounds__(256)
void out_gemm(const unsigned short* __restrict__ X, const unsigned short* __restrict__ W,
              float* __restrict__ Y) {
    __shared__ __align__(16) unsigned short As[128 * 64];
    __shared__ __align__(16) unsigned short Bs[64 * 64];
    const int bm = blockIdx.y * 128, bn = blockIdx.x * 64;

    f32x4 acc[2][4];
    #pragma unroll
    for (int ms = 0; ms < 2; ++ms)
        #pragma unroll
        for (int ns = 0; ns < 4; ++ns)
            acc[ms][ns] = (f32x4){0.f, 0.f, 0.f, 0.f};

    gemm_kloop64(X, W, As, Bs, bm, bn, acc);

    const int t = threadIdx.x, w = t >> 6, L = t & 63, quad = L >> 4, lm = L & 15;
    #pragma unroll
    for (int ms = 0; ms < 2; ++ms)
        #pragma unroll
        for (int ns = 0; ns < 4; ++ns)
            #pragma unroll
            for (int r = 0; r < 4; ++r)
                Y[(size_t)(bm + w * 32 + ms * 16 + quad * 4 + r) * D_MODEL +
                  bn + ns * 16 + lm] = acc[ms][ns][r];
}

// ---------------------------------------------------------------------------
// Flash attention, causal, S^T formulation, paired q-tiles for balance.
// Changes this round:
//  - raw s_barrier + lgkmcnt(0) only (no vmcnt drain): K/V prefetch stays in
//    flight across the per-tile barrier (reg-staged LDS writes only need lgkm)
//  - XCD-clustered block decode: each XCD owns 4 (b,h) pairs -> K+V working
//    set 2 MB fits the 4 MiB per-XCD L2 (prefetch becomes L2-hit)
//  - exp2-domain softmax (scale folded into Q) + defer-rescale (THR=8) +
//    s_setprio around MFMA clusters
// ---------------------------------------------------------------------------
__global__ __launch_bounds__(256, 3)
void attn_mfma(const unsigned short* __restrict__ Q, const unsigned short* __restrict__ K,
               const unsigned short* __restrict__ VT, unsigned short* __restrict__ A) {
    __shared__ __align__(16) unsigned short Ks[2][64 * 72];   // [buf][kv][d]
    __shared__ __align__(16) unsigned short Vs[2][64 * 72];   // [buf][d][kv]
    __shared__ __align__(16) unsigned short Ps[4 * 16 * 72];  // per-wave P^T slabs

    const int t    = threadIdx.x;
    const int w    = t >> 6;
    const int L    = t & 63;
    const int quad = L >> 4;
    const int lm   = L & 15;

    // XCD-clustered decode: dispatch round-robins consecutive ids over the 8
    // XCDs, so id&7 selects the XCD. Give each XCD 4 contiguous (b,h) pairs
    // (16 q-tile blocks each) so its L2 holds those pairs' K/V.
    const int id   = blockIdx.x;
    const int slot = id >> 3;                  // 0..63 within an XCD
    const int pair = (id & 7) * 4 + (slot >> 4);
    const int qt0  = slot & 15;
    const int h    = pair & 15;
    const int b    = pair >> 4;

    const size_t hb  = (size_t)b * SEQ * D_MODEL + h * HDK;
    const size_t vhb = (size_t)(b * NHEAD + h) * HDK;

    const int srow = t >> 2;                 // staging row 0..63
    const int sc   = (t & 3) * 16;           // element offset of this thread's 2 slots
    const unsigned short* kp = K + hb + (size_t)srow * D_MODEL + sc;
    const unsigned short* vp = VT + (vhb + srow) * SEQ + sc;
    unsigned short* ps = &Ps[w * 16 * 72];

    for (int half = 0; half < 2; ++half) {
        const int qt   = half ? 31 - qt0 : qt0;
        const int q0   = qt * 64;
        const int qrow = q0 + w * 16 + lm;

        // Q fragments (B-operand), registers for this half
        bf16x8 Qf0, Qf1;
        {
            const unsigned short* qp = Q + hb + (size_t)qrow * D_MODEL + quad * 8;
            Qf0 = *(const bf16x8*)qp;
            Qf1 = *(const bf16x8*)(qp + 32);
        }

        f32x4 Oacc[4];
        #pragma unroll
        for (int nt = 0; nt < 4; ++nt) Oacc[nt] = (f32x4){0.f, 0.f, 0.f, 0.f};
        float m_run = -INFINITY, l_run = 0.f;

        // prologue: tile 0 -> buf 0; prefetch tile 1 into regs
        float4 kr0 = *(const float4*)kp;
        float4 kr1 = *(const float4*)(kp + 8);
        float4 vr0 = *(const float4*)vp;
        float4 vr1 = *(const float4*)(vp + 8);
        *(float4*)&Ks[0][srow * 72 + sc]     = kr0;
        *(float4*)&Ks[0][srow * 72 + sc + 8] = kr1;
        *(float4*)&Vs[0][srow * 72 + sc]     = vr0;
        *(float4*)&Vs[0][srow * 72 + sc + 8] = vr1;
        if (qt >= 1) {
            kr0 = *(const float4*)(kp + (size_t)64 * D_MODEL);
            kr1 = *(const float4*)(kp + (size_t)64 * D_MODEL + 8);
            vr0 = *(const float4*)(vp + 64);
            vr1 = *(const float4*)(vp + 64 + 8);
        }
        tile_barrier();

        int bb = 0;
        for (int kt = 0; kt <= qt; ++kt) {
            const int k0 = kt * 64;
            const unsigned short* Kc = Ks[bb];
            const unsigned short* Vc = Vs[bb];
            if (kt < qt) {                      // stage kt+1 into other buffer
                unsigned short* Kn = Ks[bb ^ 1];
                unsigned short* Vn = Vs[bb ^ 1];
                *(float4*)&Kn[srow * 72 + sc]     = kr0;
                *(float4*)&Kn[srow * 72 + sc + 8] = kr1;
                *(float4*)&Vn[srow * 72 + sc]     = vr0;
                *(float4*)&Vn[srow * 72 + sc + 8] = vr1;
                if (kt + 2 <= qt) {             // prefetch kt+2
                    kr0 = *(const float4*)(kp + (size_t)(k0 + 128) * D_MODEL);
                    kr1 = *(const float4*)(kp + (size_t)(k0 + 128) * D_MODEL + 8);
                    vr0 = *(const float4*)(vp + k0 + 128);
                    vr1 = *(const float4*)(vp + k0 + 128 + 8);
                }
            }

            // ---- S^T = K Q^T (lane owns q-row lm; kv = ct*16+quad*4+r) ----
            f32x4 S[4];
            __builtin_amdgcn_s_setprio(1);
            #pragma unroll
            for (int ct = 0; ct < 4; ++ct) {
                bf16x8 a0 = *(const bf16x8*)&Kc[(ct * 16 + lm) * 72 + quad * 8];
                bf16x8 a1 = *(const bf16x8*)&Kc[(ct * 16 + lm) * 72 + 32 + quad * 8];
                f32x4 z = (f32x4){0.f, 0.f, 0.f, 0.f};
                z = __builtin_amdgcn_mfma_f32_16x16x32_bf16(a0, Qf0, z, 0, 0, 0);
                z = __builtin_amdgcn_mfma_f32_16x16x32_bf16(a1, Qf1, z, 0, 0, 0);
                S[ct] = z;
            }
            __builtin_amdgcn_s_setprio(0);

            // causal mask (diag-straddling tiles only)
            if (k0 + 63 > q0 + w * 16) {
                #pragma unroll
                for (int ct = 0; ct < 4; ++ct)
                    #pragma unroll
                    for (int r = 0; r < 4; ++r)
                        if ((k0 + ct * 16 + quad * 4 + r) > qrow)
                            S[ct][r] = -1e30f;
            }

            // ---- online softmax, exp2 domain ----
            float m = fmaxf(fmaxf(fmaxf(S[0][0], S[0][1]), fmaxf(S[0][2], S[0][3])),
                            fmaxf(fmaxf(S[1][0], S[1][1]), fmaxf(S[1][2], S[1][3])));
            m = fmaxf(m, fmaxf(fmaxf(fmaxf(S[2][0], S[2][1]), fmaxf(S[2][2], S[2][3])),
                               fmaxf(fmaxf(S[3][0], S[3][1]), fmaxf(S[3][2], S[3][3]))));
            m = fmaxf(m, __shfl_xor(m, 16));
            m = fmaxf(m, __shfl_xor(m, 32));
            // defer-rescale (T13): only rescale O when some lane's max grew
            // past 2^8; P values stay bounded by 256 (fine in f32 accum).
            if (__any(m > m_run + 8.0f)) {
                const float m_new = fmaxf(m_run, m);
                const float alpha = exp2f(m_run - m_new);
                #pragma unroll
                for (int nt = 0; nt < 4; ++nt)
                    #pragma unroll
                    for (int r = 0; r < 4; ++r) Oacc[nt][r] *= alpha;
                l_run *= alpha;
                m_run = m_new;
            }
            float psum = 0.f;
            #pragma unroll
            for (int ct = 0; ct < 4; ++ct)
                #pragma unroll
                for (int r = 0; r < 4; ++r) {
                    float e = exp2f(S[ct][r] - m_run);
                    S[ct][r] = e;
                    psum += e;
                }
            psum += __shfl_xor(psum, 16);
            psum += __shfl_xor(psum, 32);
            l_run += psum;

            // ---- P^T -> wave-private slab (v_perm truncation pack) ----
            #pragma unroll
            for (int ct = 0; ct < 4; ++ct) {
                uint2 pw = make_uint2(pack_hi(S[ct][0], S[ct][1]),
                                      pack_hi(S[ct][2], S[ct][3]));
                *(uint2*)&ps[lm * 72 + ct * 16 + quad * 4] = pw;
            }
            bf16x8 Pb0 = *(const bf16x8*)&ps[lm * 72 + quad * 8];
            bf16x8 Pb1 = *(const bf16x8*)&ps[lm * 72 + 32 + quad * 8];

            // ---- O^T += V^T P^T ----
            __builtin_amdgcn_s_setprio(1);
            #pragma unroll
            for (int nt = 0; nt < 4; ++nt) {
                bf16x8 a0 = *(const bf16x8*)&Vc[(nt * 16 + lm) * 72 + quad * 8];
                bf16x8 a1 = *(const bf16x8*)&Vc[(nt * 16 + lm) * 72 + 32 + quad * 8];
                f32x4 o = Oacc[nt];
                o = __builtin_amdgcn_mfma_f32_16x16x32_bf16(a0, Pb0, o, 0, 0, 0);
                o = __builtin_amdgcn_mfma_f32_16x16x32_bf16(a1, Pb1, o, 0, 0, 0);
                Oacc[nt] = o;
            }
            __builtin_amdgcn_s_setprio(0);

            tile_barrier();                    // single barrier per tile, no vmcnt drain
            bb ^= 1;
        }

        // ---- epilogue: O^T/l -> slab [q][d] -> coalesced stores ----
        const float inv_l = 1.f / l_run;
        #pragma unroll
        for (int nt = 0; nt < 4; ++nt) {
            ushort4 pk = make_ushort4(f2bf(Oacc[nt][0] * inv_l), f2bf(Oacc[nt][1] * inv_l),
                                      f2bf(Oacc[nt][2] * inv_l), f2bf(Oacc[nt][3] * inv_l));
            *(ushort4*)&ps[lm * 72 + nt * 16 + quad * 4] = pk;
        }
        #pragma unroll
        for (int p = 0; p < 2; ++p) {
            int qr = p * 8 + (L >> 3);
            int dc = (L & 7) * 8;
            uint4 val = *(const uint4*)&ps[qr * 72 + dc];
            *(uint4*)&A[hb + (size_t)(q0 + w * 16 + qr) * D_MODEL + dc] = val;
        }
    }
}

// ---------------------------------------------------------------------------
extern "C" void kernel_launch(void* const* d_in, const int* in_sizes, int n_in,
                              void* d_out, int out_size, void* d_ws, size_t ws_size,
                              hipStream_t stream) {
    const float* q  = (const float*)d_in[0];
    const float* k  = (const float*)d_in[1];
    const float* v  = (const float*)d_in[2];
    const float* Wq = (const float*)d_in[4];
    const float* Wk = (const float*)d_in[5];
    const float* Wv = (const float*)d_in[6];
    const float* Wo = (const float*)d_in[7];
    float* out = (float*)d_out;

    char* ws = (char*)d_ws;
    const size_t MB = 1024 * 1024;
    unsigned short* qb  = (unsigned short*)(ws + 0 * MB);
    unsigned short* kb  = (unsigned short*)(ws + 8 * MB);
    unsigned short* vb  = (unsigned short*)(ws + 16 * MB);
    unsigned short* wqb = (unsigned short*)(ws + 24 * MB);
    unsigned short* wkb = (unsigned short*)(ws + 26 * MB);
    unsigned short* wvb = (unsigned short*)(ws + 28 * MB);
    unsigned short* wob = (unsigned short*)(ws + 30 * MB);
    unsigned short* Qp  = (unsigned short*)(ws + 32 * MB);
    unsigned short* Kp  = (unsigned short*)(ws + 40 * MB);
    unsigned short* VTp = (unsigned short*)(ws + 48 * MB);
    unsigned short* Ap  = (unsigned short*)(ws + 56 * MB);

    const int nX8 = BS * D_MODEL / 8;
    const int nW8 = D_MODEL * D_MODEL / 8;
    cast_act<<<dim3(nX8 / 256, 3), 256, 0, stream>>>(q, k, v, qb, kb, vb, nX8);
    cast_wt <<<dim3(nW8 / 256, 4), 256, 0, stream>>>(Wq, Wk, Wv, Wo, wqb, wkb, wvb, wob, nW8);

    proj_gemm<<<dim3(D_MODEL / 128, BS / 128, 3), 256, 0, stream>>>(
        qb, kb, vb, wqb, wkb, wvb, Qp, Kp, VTp);

    attn_mfma<<<dim3(512), 256, 0, stream>>>(Qp, Kp, VTp, Ap);

    out_gemm<<<dim3(D_MODEL / 64, BS / 128), 256, 0, stream>>>(Ap, wob, out);
}

// Round 2
// 227.525 us; speedup vs baseline: 1.0076x; 1.0076x over previous
//
#include <hip/hip_runtime.h>
#include <hip/hip_bf16.h>

#define D_MODEL 1024
#define NHEAD   16
#define HDK     64
#define SEQ     2048
#define BATCH   2
#define BS      (BATCH * SEQ)

typedef __attribute__((ext_vector_type(8))) short bf16x8;
typedef __attribute__((ext_vector_type(4))) float f32x4;

__device__ __forceinline__ unsigned short f2bf(float f) {
    unsigned u = __builtin_bit_cast(unsigned, f);
    u += 0x7fffu + ((u >> 16) & 1u);          // round-to-nearest-even
    return (unsigned short)(u >> 16);
}

// pack hi16(x):hi16(y) -> (hi16(y)<<16)|hi16(x) with one v_perm_b32 (truncation)
__device__ __forceinline__ unsigned pack_hi(float x, float y) {
    return __builtin_amdgcn_perm(__builtin_bit_cast(unsigned, y),
                                 __builtin_bit_cast(unsigned, x), 0x07060302u);
}

// guaranteed-native 2^x (round 1 showed exp2f() can lower to a slow libcall)
__device__ __forceinline__ float exp2_fast(float x) {
    float r;
    asm("v_exp_f32 %0, %1" : "=v"(r) : "v"(x));
    return r;
}

typedef const void __attribute__((address_space(1))) gas_void;
typedef void __attribute__((address_space(3))) las_void;

__device__ __forceinline__ void gll16(const void* g, void* l) {
    __builtin_amdgcn_global_load_lds((gas_void*)g, (las_void*)l, 16, 0, 0);
}

// ---------------------------------------------------------------------------
// fp32 -> bf16 casts
// ---------------------------------------------------------------------------
__device__ __forceinline__ void cast_body(const float* __restrict__ src,
                                          unsigned short* __restrict__ dst, int i) {
    const float4* p = (const float4*)src + (size_t)i * 2;
    float4 a = p[0], b = p[1];
    ushort4 lo = make_ushort4(f2bf(a.x), f2bf(a.y), f2bf(a.z), f2bf(a.w));
    ushort4 hi = make_ushort4(f2bf(b.x), f2bf(b.y), f2bf(b.z), f2bf(b.w));
    ushort4* q = (ushort4*)dst + (size_t)i * 2;
    q[0] = lo; q[1] = hi;
}

__global__ __launch_bounds__(256)
void cast_act(const float* a, const float* b, const float* c,
              unsigned short* oa, unsigned short* ob, unsigned short* oc, int n8) {
    int i = blockIdx.x * 256 + threadIdx.x;
    if (i >= n8) return;
    const float* s = blockIdx.y == 0 ? a : blockIdx.y == 1 ? b : c;
    unsigned short* d = blockIdx.y == 0 ? oa : blockIdx.y == 1 ? ob : oc;
    cast_body(s, d, i);
}

__global__ __launch_bounds__(256)
void cast_wt(const float* a, const float* b, const float* c, const float* dd,
             unsigned short* oa, unsigned short* ob, unsigned short* oc, unsigned short* od, int n8) {
    int i = blockIdx.x * 256 + threadIdx.x;
    if (i >= n8) return;
    const float* s = blockIdx.y == 0 ? a : blockIdx.y == 1 ? b : blockIdx.y == 2 ? c : dd;
    unsigned short* d = blockIdx.y == 0 ? oa : blockIdx.y == 1 ? ob : blockIdx.y == 2 ? oc : od;
    cast_body(s, d, i);
}

// ---------------------------------------------------------------------------
// GEMM K-loop, BM=128 BN=128 BK=64, 256 thr, wave -> 64x64 quadrant.
// ---------------------------------------------------------------------------
__device__ __forceinline__ void gemm_kloop128(const unsigned short* __restrict__ X,
                                              const unsigned short* __restrict__ W,
                                              unsigned short* As, unsigned short* Bs,
                                              int bm, int bn, f32x4 acc[4][4]) {
    const int t    = threadIdx.x;
    const int w    = t >> 6;
    const int L    = t & 63;
    const int quad = L >> 4;
    const int lm   = L & 15;
    const int r8   = L >> 3;
    const int sl   = L & 7;
    const int xcol = ((sl ^ r8) & 7) * 8;
    const int wr   = (w >> 1) * 64;
    const int wc   = (w & 1) * 64;

    for (int kt = 0; kt < D_MODEL; kt += 64) {
        __syncthreads();
        #pragma unroll
        for (int i = 0; i < 4; ++i) {
            int c = w * 4 + i;
            gll16(X + (size_t)(bm + c * 8 + r8) * D_MODEL + kt + xcol, &As[c * 512]);
        }
        #pragma unroll
        for (int i = 0; i < 4; ++i) {
            int c = w * 4 + i;
            gll16(W + (size_t)(bn + c * 8 + r8) * D_MODEL + kt + xcol, &Bs[c * 512]);
        }
        __syncthreads();

        #pragma unroll
        for (int ch = 0; ch < 2; ++ch) {
            bf16x8 af[4], bfr[4];
            #pragma unroll
            for (int ms = 0; ms < 4; ++ms) {
                int row = wr + ms * 16 + lm;
                af[ms] = *(const bf16x8*)&As[row * 64 + (((ch * 4 + quad) ^ (row & 7)) * 8)];
            }
            #pragma unroll
            for (int ns = 0; ns < 4; ++ns) {
                int row = wc + ns * 16 + lm;
                bfr[ns] = *(const bf16x8*)&Bs[row * 64 + (((ch * 4 + quad) ^ (row & 7)) * 8)];
            }
            #pragma unroll
            for (int ms = 0; ms < 4; ++ms)
                #pragma unroll
                for (int ns = 0; ns < 4; ++ns)
                    acc[ms][ns] = __builtin_amdgcn_mfma_f32_16x16x32_bf16(
                        af[ms], bfr[ns], acc[ms][ns], 0, 0, 0);
        }
    }
}

// BM=128 BN=64 variant (more blocks for the small out_gemm)
__device__ __forceinline__ void gemm_kloop64(const unsigned short* __restrict__ X,
                                             const unsigned short* __restrict__ W,
                                             unsigned short* As, unsigned short* Bs,
                                             int bm, int bn, f32x4 acc[2][4]) {
    const int t    = threadIdx.x;
    const int w    = t >> 6;
    const int L    = t & 63;
    const int quad = L >> 4;
    const int lm   = L & 15;
    const int r8   = L >> 3;
    const int sl   = L & 7;
    const int xcol = ((sl ^ r8) & 7) * 8;

    for (int kt = 0; kt < D_MODEL; kt += 64) {
        __syncthreads();
        #pragma unroll
        for (int i = 0; i < 4; ++i) {
            int c = w * 4 + i;
            gll16(X + (size_t)(bm + c * 8 + r8) * D_MODEL + kt + xcol, &As[c * 512]);
        }
        #pragma unroll
        for (int i = 0; i < 2; ++i) {
            int c = w * 2 + i;
            gll16(W + (size_t)(bn + c * 8 + r8) * D_MODEL + kt + xcol, &Bs[c * 512]);
        }
        __syncthreads();

        #pragma unroll
        for (int ch = 0; ch < 2; ++ch) {
            bf16x8 af[2], bfr[4];
            #pragma unroll
            for (int ms = 0; ms < 2; ++ms) {
                int row = w * 32 + ms * 16 + lm;
                af[ms] = *(const bf16x8*)&As[row * 64 + (((ch * 4 + quad) ^ (row & 7)) * 8)];
            }
            #pragma unroll
            for (int ns = 0; ns < 4; ++ns) {
                int row = ns * 16 + lm;
                bfr[ns] = *(const bf16x8*)&Bs[row * 64 + (((ch * 4 + quad) ^ (row & 7)) * 8)];
            }
            #pragma unroll
            for (int ms = 0; ms < 2; ++ms)
                #pragma unroll
                for (int ns = 0; ns < 4; ++ns)
                    acc[ms][ns] = __builtin_amdgcn_mfma_f32_16x16x32_bf16(
                        af[ms], bfr[ns], acc[ms][ns], 0, 0, 0);
        }
    }
}

// ---------------------------------------------------------------------------
// Fused Q/K/V projections. z=0: Q (x 0.125*log2(e) -> exp2-domain softmax,
// row-major), z=1: K (row-major), z=2: V transposed per head.
// ---------------------------------------------------------------------------
__global__ __launch_bounds__(256, 3)
void proj_gemm(const unsigned short* __restrict__ qx, const unsigned short* __restrict__ kx,
               const unsigned short* __restrict__ vx, const unsigned short* __restrict__ wq,
               const unsigned short* __restrict__ wk, const unsigned short* __restrict__ wv,
               unsigned short* __restrict__ Qp, unsigned short* __restrict__ Kp,
               unsigned short* __restrict__ VT) {
    __shared__ __align__(16) unsigned short As[128 * 64];
    __shared__ __align__(16) unsigned short Bs[128 * 64];

    const int p = blockIdx.z;
    const unsigned short* X = p == 0 ? qx : p == 1 ? kx : vx;
    const unsigned short* W = p == 0 ? wq : p == 1 ? wk : wv;
    const int bm = blockIdx.y * 128, bn = blockIdx.x * 128;

    f32x4 acc[4][4];
    #pragma unroll
    for (int ms = 0; ms < 4; ++ms)
        #pragma unroll
        for (int ns = 0; ns < 4; ++ns)
            acc[ms][ns] = (f32x4){0.f, 0.f, 0.f, 0.f};

    gemm_kloop128(X, W, As, Bs, bm, bn, acc);

    const int t = threadIdx.x, w = t >> 6, L = t & 63, quad = L >> 4, lm = L & 15;
    const int wr = (w >> 1) * 64, wc = (w & 1) * 64;
    if (p == 2) {
        const int b    = bm >> 11;
        const int s_in = (bm & (SEQ - 1)) + wr;
        #pragma unroll
        for (int ms = 0; ms < 4; ++ms)
            #pragma unroll
            for (int ns = 0; ns < 4; ++ns) {
                int dg = bn + wc + ns * 16 + lm;
                int h  = dg >> 6, d = dg & 63;
                ushort4 pk = make_ushort4(f2bf(acc[ms][ns][0]), f2bf(acc[ms][ns][1]),
                                          f2bf(acc[ms][ns][2]), f2bf(acc[ms][ns][3]));
                *(ushort4*)&VT[((size_t)((b * NHEAD + h) * HDK + d)) * SEQ +
                               s_in + ms * 16 + quad * 4] = pk;
            }
    } else {
        unsigned short* Y = p == 0 ? Qp : Kp;
        // 0.125 * log2(e): softmax runs in exp2 domain (saves a v_mul per exp)
        const float scl = p == 0 ? 0.18033688011112042f : 1.0f;
        #pragma unroll
        for (int ms = 0; ms < 4; ++ms)
            #pragma unroll
            for (int ns = 0; ns < 4; ++ns)
                #pragma unroll
                for (int r = 0; r < 4; ++r)
                    Y[(size_t)(bm + wr + ms * 16 + quad * 4 + r) * D_MODEL +
                      bn + wc + ns * 16 + lm] = f2bf(acc[ms][ns][r] * scl);
    }
}

__global__ __launch_bounds__(256)
void out_gemm(const unsigned short* __restrict__ X, const unsigned short* __restrict__ W,
              float* __restrict__ Y) {
    __shared__ __align__(16) unsigned short As[128 * 64];
    __shared__ __align__(16) unsigned short Bs[64 * 64];
    const int bm = blockIdx.y * 128, bn = blockIdx.x * 64;

    f32x4 acc[2][4];
    #pragma unroll
    for (int ms = 0; ms < 2; ++ms)
        #pragma unroll
        for (int ns = 0; ns < 4; ++ns)
            acc[ms][ns] = (f32x4){0.f, 0.f, 0.f, 0.f};

    gemm_kloop64(X, W, As, Bs, bm, bn, acc);

    const int t = threadIdx.x, w = t >> 6, L = t & 63, quad = L >> 4, lm = L & 15;
    #pragma unroll
    for (int ms = 0; ms < 2; ++ms)
        #pragma unroll
        for (int ns = 0; ns < 4; ++ns)
            #pragma unroll
            for (int r = 0; r < 4; ++r)
                Y[(size_t)(bm + w * 32 + ms * 16 + quad * 4 + r) * D_MODEL +
                  bn + ns * 16 + lm] = acc[ms][ns][r];
}

// ---------------------------------------------------------------------------
// Flash attention, causal, S^T formulation.
// Round-2 changes (latency-bound diagnosis):
//  - 1024 single-q-tile blocks, longest-first within XCD clusters; LDS 40 KB
//    -> 3 blocks/CU capacity with hardware backfill (was 2 resident).
//  - lane-local online softmax: per-iter cross-lane ops = ZERO on the common
//    path (max-reduce only when defer-rescale triggers; l reduced once in
//    the epilogue -- alpha is quad-group-uniform so per-lane partials stay
//    consistent).
//  - K/V staging via global_load_lds into XOR-swizzled 64-wide tiles (same
//    pattern as gemm_kloop): no reg round-trip, -16 VGPR, fewer LDS writes.
//  - native v_exp_f32 via asm (round 1 showed exp2f() -> libcall, VALU +12pt).
// ---------------------------------------------------------------------------
__global__ __launch_bounds__(256, 3)
void attn_mfma(const unsigned short* __restrict__ Q, const unsigned short* __restrict__ K,
               const unsigned short* __restrict__ VT, unsigned short* __restrict__ A) {
    __shared__ __align__(16) unsigned short Ks[2][64 * 64];   // [buf][kv][d]  (xor-swizzled)
    __shared__ __align__(16) unsigned short Vs[2][64 * 64];   // [buf][d][kv]  (xor-swizzled)
    __shared__ __align__(16) unsigned short Ps[4][16 * 64];   // per-wave P^T slabs (swizzled)

    const int t    = threadIdx.x;
    const int w    = t >> 6;
    const int L    = t & 63;
    const int quad = L >> 4;
    const int lm   = L & 15;
    const int r8   = L >> 3;
    const int sl   = L & 7;
    const int xcol = (sl ^ r8) * 8;          // pre-swizzled global column for gll16

    // XCD-clustered decode, longest-first: id&7 = XCD; each XCD owns 4 (b,h)
    // pairs x 32 q-tiles, dispatched qt descending (LPT backfill balance).
    const int id   = blockIdx.x;
    const int slot = id >> 3;                  // 0..127 within an XCD
    const int bh   = (id & 7) * 4 + (slot >> 5);
    const int qt   = 31 - (slot & 31);
    const int h    = bh & 15;
    const int b    = bh >> 4;

    const size_t hb   = (size_t)b * SEQ * D_MODEL + h * HDK;
    const size_t vrow = (size_t)(b * NHEAD + h) * HDK * SEQ;  // VT base for this head

    const unsigned short* kbase = K + hb;
    const unsigned short* vbase = VT + vrow;
    unsigned short* ps = &Ps[w][0];

    const int q0   = qt * 64;
    const int qrow = q0 + w * 16 + lm;

    // staging: wave w covers K/V rows (w*2+i)*8 + r8, i in {0,1}
    auto stage = [&](int k0, int buf) {
        #pragma unroll
        for (int i = 0; i < 2; ++i) {
            int row = (w * 2 + i) * 8 + r8;
            gll16(kbase + (size_t)(k0 + row) * D_MODEL + xcol, &Ks[buf][(w * 2 + i) * 512]);
            gll16(vbase + (size_t)row * SEQ + k0 + xcol,       &Vs[buf][(w * 2 + i) * 512]);
        }
    };

    stage(0, 0);

    // Q fragments (B-operand)
    bf16x8 Qf0, Qf1;
    {
        const unsigned short* qp = Q + hb + (size_t)qrow * D_MODEL + quad * 8;
        Qf0 = *(const bf16x8*)qp;
        Qf1 = *(const bf16x8*)(qp + 32);
    }

    f32x4 Oacc[4];
    #pragma unroll
    for (int nt = 0; nt < 4; ++nt) Oacc[nt] = (f32x4){0.f, 0.f, 0.f, 0.f};
    float m_run  = -INFINITY;
    float l_lane = 0.f;                      // per-lane partial; reduced in epilogue

    __syncthreads();                         // drains vmcnt -> tile 0 staged

    int bb = 0;
    for (int kt = 0; kt <= qt; ++kt) {
        const int k0 = kt * 64;
        const unsigned short* Kc = Ks[bb];
        const unsigned short* Vc = Vs[bb];
        if (kt < qt) stage(k0 + 64, bb ^ 1);   // async, drained at iter-end barrier

        // ---- S^T = K Q^T (lane owns q-row lm; kv = ct*16+quad*4+r) ----
        f32x4 S[4];
        __builtin_amdgcn_s_setprio(1);
        #pragma unroll
        for (int ct = 0; ct < 4; ++ct) {
            bf16x8 a0 = *(const bf16x8*)&Kc[(ct * 16 + lm) * 64 + ((quad ^ (lm & 7)) * 8)];
            bf16x8 a1 = *(const bf16x8*)&Kc[(ct * 16 + lm) * 64 + (((4 + quad) ^ (lm & 7)) * 8)];
            f32x4 z = (f32x4){0.f, 0.f, 0.f, 0.f};
            z = __builtin_amdgcn_mfma_f32_16x16x32_bf16(a0, Qf0, z, 0, 0, 0);
            z = __builtin_amdgcn_mfma_f32_16x16x32_bf16(a1, Qf1, z, 0, 0, 0);
            S[ct] = z;
        }
        __builtin_amdgcn_s_setprio(0);

        // causal mask (diag-straddling tiles only)
        if (k0 + 63 > q0 + w * 16) {
            #pragma unroll
            for (int ct = 0; ct < 4; ++ct)
                #pragma unroll
                for (int r = 0; r < 4; ++r)
                    if ((k0 + ct * 16 + quad * 4 + r) > qrow)
                        S[ct][r] = -1e30f;
        }

        // ---- lane-local online softmax, exp2 domain ----
        float ml = fmaxf(fmaxf(fmaxf(S[0][0], S[0][1]), fmaxf(S[0][2], S[0][3])),
                         fmaxf(fmaxf(S[1][0], S[1][1]), fmaxf(S[1][2], S[1][3])));
        ml = fmaxf(ml, fmaxf(fmaxf(fmaxf(S[2][0], S[2][1]), fmaxf(S[2][2], S[2][3])),
                             fmaxf(fmaxf(S[3][0], S[3][1]), fmaxf(S[3][2], S[3][3]))));
        // defer-rescale: cross-lane reduce + O rescale only when a lane's max
        // outgrew the bound (P stays <= 2^8 in f32 accumulation otherwise).
        if (__any(ml > m_run + 8.0f)) {
            float m = fmaxf(ml, __shfl_xor(ml, 16));
            m = fmaxf(m, __shfl_xor(m, 32));
            const float m_new = fmaxf(m_run, m);
            const float alpha = exp2_fast(m_run - m_new);
            #pragma unroll
            for (int nt = 0; nt < 4; ++nt)
                #pragma unroll
                for (int r = 0; r < 4; ++r) Oacc[nt][r] *= alpha;
            l_lane *= alpha;
            m_run = m_new;
        }
        float psum = 0.f;
        #pragma unroll
        for (int ct = 0; ct < 4; ++ct)
            #pragma unroll
            for (int r = 0; r < 4; ++r) {
                float e = exp2_fast(S[ct][r] - m_run);
                S[ct][r] = e;
                psum += e;
            }
        l_lane += psum;                      // per-lane; no shuffle

        // ---- P^T -> wave-private slab (swizzled, v_perm truncation pack) ----
        #pragma unroll
        for (int ct = 0; ct < 4; ++ct) {
            uint2 pw = make_uint2(pack_hi(S[ct][0], S[ct][1]),
                                  pack_hi(S[ct][2], S[ct][3]));
            int lc = 2 * ct + (quad >> 1);
            *(uint2*)&ps[lm * 64 + ((lc ^ (lm & 7)) * 8) + (quad & 1) * 4] = pw;
        }
        bf16x8 Pb0 = *(const bf16x8*)&ps[lm * 64 + ((quad ^ (lm & 7)) * 8)];
        bf16x8 Pb1 = *(const bf16x8*)&ps[lm * 64 + (((4 + quad) ^ (lm & 7)) * 8)];

        // ---- O^T += V^T P^T ----
        __builtin_amdgcn_s_setprio(1);
        #pragma unroll
        for (int nt = 0; nt < 4; ++nt) {
            bf16x8 a0 = *(const bf16x8*)&Vc[(nt * 16 + lm) * 64 + ((quad ^ (lm & 7)) * 8)];
            bf16x8 a1 = *(const bf16x8*)&Vc[(nt * 16 + lm) * 64 + (((4 + quad) ^ (lm & 7)) * 8)];
            f32x4 o = Oacc[nt];
            o = __builtin_amdgcn_mfma_f32_16x16x32_bf16(a0, Pb0, o, 0, 0, 0);
            o = __builtin_amdgcn_mfma_f32_16x16x32_bf16(a1, Pb1, o, 0, 0, 0);
            Oacc[nt] = o;
        }
        __builtin_amdgcn_s_setprio(0);

        __syncthreads();                     // buf swap: drains gll16 (vmcnt) + ds
        bb ^= 1;
    }

    // ---- epilogue: reduce l across the quad-group (once), normalize, store ----
    float l = l_lane + __shfl_xor(l_lane, 16);
    l += __shfl_xor(l, 32);
    const float inv_l = 1.f / l;
    #pragma unroll
    for (int nt = 0; nt < 4; ++nt) {
        ushort4 pk = make_ushort4(f2bf(Oacc[nt][0] * inv_l), f2bf(Oacc[nt][1] * inv_l),
                                  f2bf(Oacc[nt][2] * inv_l), f2bf(Oacc[nt][3] * inv_l));
        int lc = 2 * nt + (quad >> 1);
        *(ushort4*)&ps[lm * 64 + ((lc ^ (lm & 7)) * 8) + (quad & 1) * 4] = pk;
    }
    #pragma unroll
    for (int p = 0; p < 2; ++p) {
        int qr = p * 8 + r8;
        int dc = sl * 8;
        uint4 val = *(const uint4*)&ps[qr * 64 + ((sl ^ (qr & 7)) * 8)];
        *(uint4*)&A[hb + (size_t)(q0 + w * 16 + qr) * D_MODEL + dc] = val;
    }
}

// ---------------------------------------------------------------------------
extern "C" void kernel_launch(void* const* d_in, const int* in_sizes, int n_in,
                              void* d_out, int out_size, void* d_ws, size_t ws_size,
                              hipStream_t stream) {
    const float* q  = (const float*)d_in[0];
    const float* k  = (const float*)d_in[1];
    const float* v  = (const float*)d_in[2];
    const float* Wq = (const float*)d_in[4];
    const float* Wk = (const float*)d_in[5];
    const float* Wv = (const float*)d_in[6];
    const float* Wo = (const float*)d_in[7];
    float* out = (float*)d_out;

    char* ws = (char*)d_ws;
    const size_t MB = 1024 * 1024;
    unsigned short* qb  = (unsigned short*)(ws + 0 * MB);
    unsigned short* kb  = (unsigned short*)(ws + 8 * MB);
    unsigned short* vb  = (unsigned short*)(ws + 16 * MB);
    unsigned short* wqb = (unsigned short*)(ws + 24 * MB);
    unsigned short* wkb = (unsigned short*)(ws + 26 * MB);
    unsigned short* wvb = (unsigned short*)(ws + 28 * MB);
    unsigned short* wob = (unsigned short*)(ws + 30 * MB);
    unsigned short* Qp  = (unsigned short*)(ws + 32 * MB);
    unsigned short* Kp  = (unsigned short*)(ws + 40 * MB);
    unsigned short* VTp = (unsigned short*)(ws + 48 * MB);
    unsigned short* Ap  = (unsigned short*)(ws + 56 * MB);

    const int nX8 = BS * D_MODEL / 8;
    const int nW8 = D_MODEL * D_MODEL / 8;
    cast_act<<<dim3(nX8 / 256, 3), 256, 0, stream>>>(q, k, v, qb, kb, vb, nX8);
    cast_wt <<<dim3(nW8 / 256, 4), 256, 0, stream>>>(Wq, Wk, Wv, Wo, wqb, wkb, wvb, wob, nW8);

    proj_gemm<<<dim3(D_MODEL / 128, BS / 128, 3), 256, 0, stream>>>(
        qb, kb, vb, wqb, wkb, wvb, Qp, Kp, VTp);

    attn_mfma<<<dim3(1024), 256, 0, stream>>>(Qp, Kp, VTp, Ap);

    out_gemm<<<dim3(D_MODEL / 64, BS / 128), 256, 0, stream>>>(Ap, wob, out);
}